// Round 10
// baseline (1341.476 us; speedup 1.0000x reference)
//
#include <hip/hip_runtime.h>

#define N_NODES 100000
#define N_EDGES 1600000
#define DIM 128

// bucketing: 64 nodes per bucket
#define NPB 64
#define NBUCK 1563            // ceil(100000 / 64)
#define EPB 4096              // edges per block in hist/fill
#define NBLK_E 391            // ceil(1600000 / 4096)
#define NBLK_G 1563           // fallback fp32 gemm blocks (GR=64)
#define NBLK_M 782            // mfma gemm blocks (GMR=128)

// ---------------- workspace layout (bytes, 128-aligned) --------------------
#define OFF_H       0                    // bf16 [N_NODES][128]    25,600,000
#define OFF_BCNT    25600000             // int [NBUCK]   (pad 6272)
#define OFF_BBASE   25606272             // int [NBUCK+1] (pad 6272)
#define OFF_BCUR    25612544             // int [NBUCK]   (pad 6272)
#define OFF_EPACK   25618816             // uint2 [N_EDGES]        12,800,000
#define OFF_WPL     38418816             // uint [16384] W bf16 hi/lo  65,536
#define WS_NEED     38484352

typedef __attribute__((ext_vector_type(8))) __bf16 bf16x8;
typedef __attribute__((ext_vector_type(4))) float  f32x4;

union U4B8 { uint4 u; bf16x8 v; };
union B8   { __bf16 b[8]; bf16x8 v; };

static __device__ __forceinline__ unsigned short f2bf(float f) {
    union { float f; unsigned u; } a; a.f = f;
    unsigned r = a.u + 0x7fffu + ((a.u >> 16) & 1u);  // round-to-nearest-even
    return (unsigned short)(r >> 16);
}

static __device__ __forceinline__ float bf2f(unsigned short h) {
    return __uint_as_float((unsigned)h << 16);
}

static __device__ __forceinline__ float bflo(unsigned b) {
    return __uint_as_float(b << 16);
}
static __device__ __forceinline__ float bfhi(unsigned b) {
    return __uint_as_float(b & 0xffff0000u);
}

// ---------------------------------------------------------------------------
// zero helper (fallback path)
// ---------------------------------------------------------------------------
__global__ __launch_bounds__(256) void zero_out_kernel(float4* __restrict__ out) {
    int i = blockIdx.x * 256 + threadIdx.x;
    if (i < N_NODES * DIM / 4) out[i] = make_float4(0.f, 0.f, 0.f, 0.f);
}

// ---------------------------------------------------------------------------
// Prep (round-8 layout): blocks 0..15 split W into bf16 hi/lo planes, stored
// PRE-SWIZZLED per K-half so gemm blocks do a LINEAR 32 KB LDS copy and read
// with the XOR pattern (2-way conflict = free). Blocks 16..22 zero bcnt.
// ---------------------------------------------------------------------------
__global__ __launch_bounds__(256) void prep_kernel(
        const float4* __restrict__ W4, unsigned* __restrict__ wpl,
        int* __restrict__ bcnt)
{
    const int b = blockIdx.x;
    if (b < 16) {
        int idx = b * 256 + threadIdx.x;       // 0..4095 float4s of W
        int j   = idx >> 5;                    // W row (output col) 0..127
        int c4  = idx & 31;
        float4 v = W4[idx];
        unsigned short hx = f2bf(v.x), hy = f2bf(v.y);
        unsigned short hz = f2bf(v.z), hw = f2bf(v.w);
        unsigned short lx = f2bf(v.x - bf2f(hx));
        unsigned short ly = f2bf(v.y - bf2f(hy));
        unsigned short lz = f2bf(v.z - bf2f(hz));
        unsigned short lw = f2bf(v.w - bf2f(hw));
        int dg = c4 * 2;                       // global k-dword 0..63 (even)
        int kc = dg >> 5;                      // K-half
        int dl = dg & 31;                      // dword within half (even)
        int p  = dl ^ ((j & 7) << 2);          // swizzled (pair stays adjacent)
        int base = kc * 8192 + j * 32;
        wpl[base + p]            = (unsigned)hx | ((unsigned)hy << 16);
        wpl[base + p + 1]        = (unsigned)hz | ((unsigned)hw << 16);
        wpl[base + 4096 + p]     = (unsigned)lx | ((unsigned)ly << 16);
        wpl[base + 4096 + p + 1] = (unsigned)lz | ((unsigned)lw << 16);
    } else {
        int i = (b - 16) * 256 + threadIdx.x;
        if (i < NBUCK) bcnt[i] = 0;
    }
}

// ---------------------------------------------------------------------------
// Bucket histogram: per-block LDS hist over NBUCK buckets, phase-staggered
// global flush.
// ---------------------------------------------------------------------------
__global__ __launch_bounds__(256) void bucket_hist_kernel(
        const int* __restrict__ dst, int* __restrict__ bcnt)
{
    __shared__ int lh[NBUCK];
    const int t = threadIdx.x;
    const int e0 = blockIdx.x * EPB;

    for (int i = t; i < NBUCK; i += 256) lh[i] = 0;
    __syncthreads();
#pragma unroll
    for (int r = 0; r < 16; ++r) {
        int e = e0 + (r << 8) + t;
        if (e < N_EDGES) atomicAdd(&lh[dst[e] >> 6], 1);
    }
    __syncthreads();
    const int phase = (blockIdx.x * 613) % NBUCK;
    for (int k = t; k < NBUCK; k += 256) {
        int i = k + phase; if (i >= NBUCK) i -= NBUCK;
        int c = lh[i];
        if (c) atomicAdd(&bcnt[i], c);
    }
}

// ---------------------------------------------------------------------------
// Single-block scan of bucket counts -> bbase (exclusive, +sentinel), bcur.
// ---------------------------------------------------------------------------
__global__ __launch_bounds__(256) void bucket_scan_kernel(
        const int* __restrict__ bcnt, int* __restrict__ bbase,
        int* __restrict__ bcur)
{
    __shared__ int wsh[4];
    const int t = threadIdx.x, lane = t & 63, wv = t >> 6;
    int c[8]; int s = 0;
#pragma unroll
    for (int i = 0; i < 8; ++i) {
        int idx = t * 8 + i;
        c[i] = (idx < NBUCK) ? bcnt[idx] : 0;
        s += c[i];
    }
    int v = s;
#pragma unroll
    for (int off = 1; off < 64; off <<= 1) {
        int u = __shfl_up(v, off, 64);
        if (lane >= off) v += u;
    }
    if (lane == 63) wsh[wv] = v;
    __syncthreads();
    int we = 0;
#pragma unroll
    for (int w = 0; w < 4; ++w) we += (w < wv) ? wsh[w] : 0;
    int run = we + (v - s);
#pragma unroll
    for (int i = 0; i < 8; ++i) {
        int idx = t * 8 + i;
        if (idx < NBUCK) { bbase[idx] = run; bcur[idx] = run; }
        run += c[i];
    }
    if (t == 0) bbase[NBUCK] = N_EDGES;
}

// ---------------------------------------------------------------------------
// Fused MFMA-GEMM | bucket-fill kernel (round-8 proven structure).
//  blocks [0, NBLK_E)            : fill 4096 edges into bucket regions
//  blocks [NBLK_E, NBLK_E+NBLK_M): 128x128 tile of h = bf16(x @ W^T)
// ---------------------------------------------------------------------------
#define GMR 128
__global__ __launch_bounds__(256) void gemm_fill_kernel(
        const float4* __restrict__ x4,        // [N_NODES][32]
        const unsigned* __restrict__ wpl,     // precomputed W planes (swizzled)
        unsigned short* __restrict__ hb16,    // [N_NODES][128] bf16 bits
        const int* __restrict__ src,
        const int* __restrict__ dst,
        const float* __restrict__ vals,
        int* __restrict__ bcur,
        uint2* __restrict__ ep)
{
    __shared__ alignas(16) unsigned smem[8192];   // 32 KB shared by both roles
    const int t = threadIdx.x;

    if (blockIdx.x < NBLK_E) {
        // ---------------- fill role ----------------
        int* lh    = (int*)smem;            // [NBUCK]
        int* lbase = (int*)smem + NBUCK;    // [NBUCK]  (12.5 KB total)
        const int e0 = blockIdx.x * EPB;

        for (int i = t; i < NBUCK; i += 256) lh[i] = 0;
        __syncthreads();
#pragma unroll
        for (int r = 0; r < 16; ++r) {
            int e = e0 + (r << 8) + t;
            if (e < N_EDGES) atomicAdd(&lh[dst[e] >> 6], 1);
        }
        __syncthreads();
        const int phase = (blockIdx.x * 613) % NBUCK;
        for (int k = t; k < NBUCK; k += 256) {
            int i = k + phase; if (i >= NBUCK) i -= NBUCK;
            int c = lh[i];
            lbase[i] = c ? atomicAdd(&bcur[i], c) : 0;
            lh[i] = 0;    // becomes local cursor
        }
        __syncthreads();
#pragma unroll
        for (int r = 0; r < 16; ++r) {
            int e = e0 + (r << 8) + t;
            if (e < N_EDGES) {
                int d  = dst[e];
                int bk = d >> 6;
                int p  = lbase[bk] + atomicAdd(&lh[bk], 1);
                ep[p] = make_uint2((unsigned)src[e] | ((unsigned)(d & 63) << 17),
                                   __float_as_uint(vals[e]));
            }
        }
        return;
    }

    // ---------------- gemm role (LDS-staged, round-8) ----------------
    unsigned* lw = smem;                        // hi[128][32] + lo[128][32]

    const int lane = t & 63;
    const int w    = t >> 6;
    const int col  = lane & 15;
    const int kg   = lane >> 4;                 // k-group 0..3
    const int r0   = (blockIdx.x - NBLK_E) * GMR;

    const int arow0 = r0 + (w << 4) + col;
    const int arow1 = arow0 + 64;
    const bool ok0 = arow0 < N_NODES;
    const bool ok1 = arow1 < N_NODES;

    f32x4 acc[2][8];
#pragma unroll
    for (int rt = 0; rt < 2; ++rt)
#pragma unroll
        for (int jt = 0; jt < 8; ++jt) acc[rt][jt] = (f32x4)(0.f);

    for (int kc = 0; kc < 2; ++kc) {
        // linear 32 KB copy of this K-half's planes (8 uint4 / thread)
        const uint4* g = (const uint4*)(wpl + kc * 8192);
#pragma unroll
        for (int i = 0; i < 8; ++i)
            ((uint4*)lw)[t + 256 * i] = g[t + 256 * i];
        __syncthreads();

#pragma unroll
        for (int kh = 0; kh < 2; ++kh) {
            const int ks = kc * 2 + kh;         // 16-float k-slice 0..3

            B8 ah[2], al[2];
#pragma unroll
            for (int rt = 0; rt < 2; ++rt) {
                float4 a0 = make_float4(0.f, 0.f, 0.f, 0.f);
                float4 a1 = make_float4(0.f, 0.f, 0.f, 0.f);
                const int arow = rt ? arow1 : arow0;
                const bool ok  = rt ? ok1 : ok0;
                if (ok) {
                    a0 = x4[(size_t)arow * 32 + ks * 8 + kg * 2];
                    a1 = x4[(size_t)arow * 32 + ks * 8 + kg * 2 + 1];
                }
                float av[8] = {a0.x, a0.y, a0.z, a0.w, a1.x, a1.y, a1.z, a1.w};
#pragma unroll
                for (int e = 0; e < 8; ++e) {
                    __bf16 h = (__bf16)av[e];
                    ah[rt].b[e] = h;
                    al[rt].b[e] = (__bf16)(av[e] - (float)h);
                }
            }

            const int d0 = (kh << 4) + (kg << 2);
#pragma unroll
            for (int jt = 0; jt < 8; ++jt) {
                int j  = (jt << 4) + col;
                int p0 = d0 ^ ((j & 7) << 2);
                U4B8 bh, bl;
                bh.u = *(const uint4*)&lw[j * 32 + p0];
                bl.u = *(const uint4*)&lw[4096 + j * 32 + p0];
                acc[0][jt] = __builtin_amdgcn_mfma_f32_16x16x32_bf16(ah[0].v, bh.v, acc[0][jt], 0, 0, 0);
                acc[0][jt] = __builtin_amdgcn_mfma_f32_16x16x32_bf16(al[0].v, bh.v, acc[0][jt], 0, 0, 0);
                acc[0][jt] = __builtin_amdgcn_mfma_f32_16x16x32_bf16(ah[0].v, bl.v, acc[0][jt], 0, 0, 0);
                acc[1][jt] = __builtin_amdgcn_mfma_f32_16x16x32_bf16(ah[1].v, bh.v, acc[1][jt], 0, 0, 0);
                acc[1][jt] = __builtin_amdgcn_mfma_f32_16x16x32_bf16(al[1].v, bh.v, acc[1][jt], 0, 0, 0);
                acc[1][jt] = __builtin_amdgcn_mfma_f32_16x16x32_bf16(ah[1].v, bl.v, acc[1][jt], 0, 0, 0);
            }
        }
        __syncthreads();
    }

    // D layout: row = kg*4 + reg, col = lane&15 (verified m89)
#pragma unroll
    for (int rt = 0; rt < 2; ++rt) {
#pragma unroll
        for (int jt = 0; jt < 8; ++jt) {
#pragma unroll
            for (int r = 0; r < 4; ++r) {
                int node = r0 + rt * 64 + (w << 4) + kg * 4 + r;
                if (node < N_NODES)
                    hb16[(size_t)node * 128 + (jt << 4) + col] = f2bf(acc[rt][jt][r]);
            }
        }
    }
}

// ---------------------------------------------------------------------------
// Gather via LDS accumulation: one block per bucket. 64-node x 128-dim fp32
// accumulator tile in LDS (32 KB). Edges streamed unsorted (bucket-local),
// 8 straight-line wave-parallel h-row loads per iteration, 2 LDS
// atomicAdd f32 per lane per edge. No reorder pass, no row_ptr.
// ---------------------------------------------------------------------------
__global__ __launch_bounds__(256) void gather_lds_kernel(
        const unsigned int* __restrict__ hbits,  // [N_NODES][64]
        const int* __restrict__ bbase,           // [NBUCK+1]
        const uint2* __restrict__ ep,
        float* __restrict__ out)
{
    __shared__ float facc[NPB * DIM];            // 32 KB
    const int t = threadIdx.x;
    const int lane = t & 63;
    const int wv = t >> 6;
    const int b = blockIdx.x;

#pragma unroll
    for (int i = 0; i < 32; ++i) facc[t + 256 * i] = 0.f;
    __syncthreads();

    const int jb = bbase[b];
    const int je = bbase[b + 1];

    for (int j0 = jb + wv * 8; j0 < je; j0 += 32) {
        if (j0 + 8 <= je) {
            uint2 e0 = ep[j0+0], e1 = ep[j0+1], e2 = ep[j0+2], e3 = ep[j0+3];
            uint2 e4 = ep[j0+4], e5 = ep[j0+5], e6 = ep[j0+6], e7 = ep[j0+7];
            unsigned h0 = hbits[((size_t)(e0.x & 0x1FFFFu) << 6) + lane];
            unsigned h1 = hbits[((size_t)(e1.x & 0x1FFFFu) << 6) + lane];
            unsigned h2 = hbits[((size_t)(e2.x & 0x1FFFFu) << 6) + lane];
            unsigned h3 = hbits[((size_t)(e3.x & 0x1FFFFu) << 6) + lane];
            unsigned h4 = hbits[((size_t)(e4.x & 0x1FFFFu) << 6) + lane];
            unsigned h5 = hbits[((size_t)(e5.x & 0x1FFFFu) << 6) + lane];
            unsigned h6 = hbits[((size_t)(e6.x & 0x1FFFFu) << 6) + lane];
            unsigned h7 = hbits[((size_t)(e7.x & 0x1FFFFu) << 6) + lane];
            float v0 = __uint_as_float(e0.y), v1 = __uint_as_float(e1.y);
            float v2 = __uint_as_float(e2.y), v3 = __uint_as_float(e3.y);
            float v4 = __uint_as_float(e4.y), v5 = __uint_as_float(e5.y);
            float v6 = __uint_as_float(e6.y), v7 = __uint_as_float(e7.y);
            int n0 = (e0.x >> 17) << 7, n1 = (e1.x >> 17) << 7;
            int n2 = (e2.x >> 17) << 7, n3 = (e3.x >> 17) << 7;
            int n4 = (e4.x >> 17) << 7, n5 = (e5.x >> 17) << 7;
            int n6 = (e6.x >> 17) << 7, n7 = (e7.x >> 17) << 7;
            atomicAdd(&facc[n0 + lane * 2],     v0 * bflo(h0));
            atomicAdd(&facc[n0 + lane * 2 + 1], v0 * bfhi(h0));
            atomicAdd(&facc[n1 + lane * 2],     v1 * bflo(h1));
            atomicAdd(&facc[n1 + lane * 2 + 1], v1 * bfhi(h1));
            atomicAdd(&facc[n2 + lane * 2],     v2 * bflo(h2));
            atomicAdd(&facc[n2 + lane * 2 + 1], v2 * bfhi(h2));
            atomicAdd(&facc[n3 + lane * 2],     v3 * bflo(h3));
            atomicAdd(&facc[n3 + lane * 2 + 1], v3 * bfhi(h3));
            atomicAdd(&facc[n4 + lane * 2],     v4 * bflo(h4));
            atomicAdd(&facc[n4 + lane * 2 + 1], v4 * bfhi(h4));
            atomicAdd(&facc[n5 + lane * 2],     v5 * bflo(h5));
            atomicAdd(&facc[n5 + lane * 2 + 1], v5 * bfhi(h5));
            atomicAdd(&facc[n6 + lane * 2],     v6 * bflo(h6));
            atomicAdd(&facc[n6 + lane * 2 + 1], v6 * bfhi(h6));
            atomicAdd(&facc[n7 + lane * 2],     v7 * bflo(h7));
            atomicAdd(&facc[n7 + lane * 2 + 1], v7 * bfhi(h7));
        } else {
            for (int j = j0; j < je; ++j) {
                uint2 e0 = ep[j];
                unsigned h0 = hbits[((size_t)(e0.x & 0x1FFFFu) << 6) + lane];
                float v0 = __uint_as_float(e0.y);
                int n0 = (e0.x >> 17) << 7;
                atomicAdd(&facc[n0 + lane * 2],     v0 * bflo(h0));
                atomicAdd(&facc[n0 + lane * 2 + 1], v0 * bfhi(h0));
            }
        }
    }
    __syncthreads();

    // write out 64 node rows, coalesced float4
    const int base_node = b * NPB;
#pragma unroll
    for (int i = 0; i < 8; ++i) {
        int idx = t + 256 * i;                  // float4 index 0..2047
        int node = base_node + (idx >> 5);
        if (node < N_NODES)
            ((float4*)out)[(size_t)node * 32 + (idx & 31)] =
                *(const float4*)&facc[idx * 4];
    }
}

// ---------------------------------------------------------------------------
// Fallback path kernels (workspace too small): fp32 gemm + atomic scatter
// ---------------------------------------------------------------------------
#define GR 64
__global__ __launch_bounds__(256) void gemm_tiled_kernel(
        const float4* __restrict__ x4, const float4* __restrict__ W4,
        unsigned int* __restrict__ hbits)
{
    __shared__ alignas(16) float xs[GR][68];
    __shared__ alignas(16) float wsh[64][132];

    const int t  = threadIdx.x;
    const int tx = t & 15;
    const int ty = t >> 4;
    const int r0 = blockIdx.x * GR;

    float acc[4][8];
#pragma unroll
    for (int i = 0; i < 4; ++i)
#pragma unroll
        for (int j = 0; j < 8; ++j) acc[i][j] = 0.f;

    for (int kc = 0; kc < 2; ++kc) {
#pragma unroll
        for (int i = 0; i < 4; ++i) {
            int linear = t + 256 * i;
            int r  = linear >> 4;
            int k4 = linear & 15;
            float4 v = make_float4(0.f, 0.f, 0.f, 0.f);
            if (r0 + r < N_NODES) v = x4[(size_t)(r0 + r) * 32 + kc * 16 + k4];
            *(float4*)&xs[r][k4 * 4] = v;
        }
#pragma unroll
        for (int i = 0; i < 8; ++i) {
            int linear = t + 256 * i;
            int c  = linear >> 4;
            int k4 = linear & 15;
            float4 v = W4[(size_t)c * 32 + kc * 16 + k4];
            wsh[k4 * 4 + 0][c] = v.x;
            wsh[k4 * 4 + 1][c] = v.y;
            wsh[k4 * 4 + 2][c] = v.z;
            wsh[k4 * 4 + 3][c] = v.w;
        }
        __syncthreads();
#pragma unroll 4
        for (int kk = 0; kk < 64; ++kk) {
            float xf[4], wf[8];
#pragma unroll
            for (int i = 0; i < 4; ++i) xf[i] = xs[ty * 4 + i][kk];
            float4 wlo4 = *(const float4*)&wsh[kk][tx * 8];
            float4 whi4 = *(const float4*)&wsh[kk][tx * 8 + 4];
            wf[0] = wlo4.x; wf[1] = wlo4.y; wf[2] = wlo4.z; wf[3] = wlo4.w;
            wf[4] = whi4.x; wf[5] = whi4.y; wf[6] = whi4.z; wf[7] = whi4.w;
#pragma unroll
            for (int i = 0; i < 4; ++i)
#pragma unroll
                for (int j = 0; j < 8; ++j) acc[i][j] += xf[i] * wf[j];
        }
        __syncthreads();
    }
#pragma unroll
    for (int i = 0; i < 4; ++i) {
        int r = r0 + ty * 4 + i;
        if (r < N_NODES) {
            uint4 u;
            u.x = (unsigned)f2bf(acc[i][0]) | ((unsigned)f2bf(acc[i][1]) << 16);
            u.y = (unsigned)f2bf(acc[i][2]) | ((unsigned)f2bf(acc[i][3]) << 16);
            u.z = (unsigned)f2bf(acc[i][4]) | ((unsigned)f2bf(acc[i][5]) << 16);
            u.w = (unsigned)f2bf(acc[i][6]) | ((unsigned)f2bf(acc[i][7]) << 16);
            *(uint4*)&hbits[(size_t)r * 64 + tx * 4] = u;
        }
    }
}

__global__ __launch_bounds__(256) void scatter_kernel(
        const unsigned int* __restrict__ hbits, const float* __restrict__ vals,
        const int* __restrict__ src, const int* __restrict__ dst,
        float* __restrict__ out)
{
    const int lane = threadIdx.x & 63;
    int e = (blockIdx.x * 256 + threadIdx.x) >> 6;
    if (e >= N_EDGES) return;
    const int   s = src[e];
    const int   d = dst[e];
    const float v = vals[e];
    unsigned b = hbits[(size_t)s * 64 + lane];
    float* op = out + (size_t)d * DIM + lane * 2;
    atomicAdd(op + 0, v * bflo(b));
    atomicAdd(op + 1, v * bfhi(b));
}

// ---------------------------------------------------------------------------
extern "C" void kernel_launch(void* const* d_in, const int* in_sizes, int n_in,
                              void* d_out, int out_size, void* d_ws, size_t ws_size,
                              hipStream_t stream) {
    const float* x    = (const float*)d_in[0];
    const float* W    = (const float*)d_in[1];
    const float* vals = (const float*)d_in[2];
    const int*   src  = (const int*)d_in[3];
    const int*   dst  = (const int*)d_in[4];
    float* out = (float*)d_out;

    char* ws = (char*)d_ws;
    unsigned* hbits = (unsigned*)(ws + OFF_H);
    int*   bcnt    = (int*)(ws + OFF_BCNT);
    int*   bbase   = (int*)(ws + OFF_BBASE);
    int*   bcur    = (int*)(ws + OFF_BCUR);
    uint2* ep      = (uint2*)(ws + OFF_EPACK);
    unsigned* wpl  = (unsigned*)(ws + OFF_WPL);

    if (ws_size >= (size_t)WS_NEED) {
        prep_kernel<<<16 + 7, 256, 0, stream>>>((const float4*)W, wpl, bcnt);
        bucket_hist_kernel<<<NBLK_E, 256, 0, stream>>>(dst, bcnt);
        bucket_scan_kernel<<<1, 256, 0, stream>>>(bcnt, bbase, bcur);
        gemm_fill_kernel<<<NBLK_E + NBLK_M, 256, 0, stream>>>(
            (const float4*)x, wpl, (unsigned short*)hbits,
            src, dst, vals, bcur, ep);
        gather_lds_kernel<<<NBUCK, 256, 0, stream>>>(
            hbits, bbase, ep, out);
    } else {
        gemm_tiled_kernel<<<NBLK_G, 256, 0, stream>>>(
            (const float4*)x, (const float4*)W, hbits);
        zero_out_kernel<<<(N_NODES * DIM / 4 + 255) / 256, 256, 0, stream>>>((float4*)out);
        scatter_kernel<<<(N_EDGES * 64 + 255) / 256, 256, 0, stream>>>(
            hbits, vals, src, dst, out);
    }
}